// Round 19
// baseline (63.006 us; speedup 1.0000x reference)
//
#include <hip/hip_runtime.h>
#include <hip/hip_bf16.h>
#include <cstdint>
#include <cstddef>

#define B_ 64
#define T_ 256
#define C_ 384
#define H_ 6
#define HD_ 64

using u16 = unsigned short;
typedef __attribute__((ext_vector_type(8))) short short8;   // 8 bf16 (4 VGPR)
typedef __attribute__((ext_vector_type(4))) short short4_;  // 4 bf16 (8 B)
typedef __attribute__((ext_vector_type(4))) float f32x4;

__device__ __forceinline__ u16 f2bf(float f) {
    union { float f; uint32_t u; } x{f};
    uint32_t r = x.u + 0x7fffu + ((x.u >> 16) & 1u);
    return (u16)(r >> 16);
}

// ---------------- fused prep: cvt x, pack Wqkv (LDS transpose), cvt Wp ----------------
__global__ void k_prep(const float* __restrict__ x, const float* __restrict__ Wq,
                       const float* __restrict__ Wk, const float* __restrict__ Wv,
                       const float* __restrict__ Wp, u16* __restrict__ xb,
                       u16* __restrict__ wqkv, u16* __restrict__ wpb) {
    int bid = blockIdx.x;
    if (bid < 3072) {
        int i = (bid * 256 + threadIdx.x) * 8;
        const f32x4* p = (const f32x4*)(x + i);
        f32x4 a = p[0], b = p[1];
        short8 s;
        s[0] = (short)f2bf(a[0]); s[1] = (short)f2bf(a[1]);
        s[2] = (short)f2bf(a[2]); s[3] = (short)f2bf(a[3]);
        s[4] = (short)f2bf(b[0]); s[5] = (short)f2bf(b[1]);
        s[6] = (short)f2bf(b[2]); s[7] = (short)f2bf(b[3]);
        *(short8*)(xb + i) = s;
    } else if (bid < 3180) {
        __shared__ u16 Tt[64 * 65];
        int pb = bid - 3072;
        int which = pb / 36, rem = pb % 36;
        int h = rem / 6, cc0 = (rem % 6) * 64;
        const float* W = (which == 0) ? Wq : ((which == 1) ? Wk : Wv);
        int d = threadIdx.x & 63, cr0 = threadIdx.x >> 6;
#pragma unroll
        for (int p = 0; p < 16; ++p) {
            int cr = p * 4 + cr0;
            Tt[cr * 65 + d] = f2bf(W[(h * 384 + cc0 + cr) * 64 + d]);
        }
        __syncthreads();
        int ccl = threadIdx.x & 63, dl0 = threadIdx.x >> 6;
        int nbase = which * 384 + h * 64;
#pragma unroll
        for (int p = 0; p < 16; ++p) {
            int dl = p * 4 + dl0;
            wqkv[(size_t)(nbase + dl) * 384 + cc0 + ccl] = Tt[ccl * 65 + dl];
        }
    } else {
        int i = ((bid - 3180) * 256 + threadIdx.x) * 8;
        const f32x4* p = (const f32x4*)(Wp + i);
        f32x4 a = p[0], b = p[1];
        short8 s;
        s[0] = (short)f2bf(a[0]); s[1] = (short)f2bf(a[1]);
        s[2] = (short)f2bf(a[2]); s[3] = (short)f2bf(a[3]);
        s[4] = (short)f2bf(b[0]); s[5] = (short)f2bf(b[1]);
        s[6] = (short)f2bf(b[2]); s[7] = (short)f2bf(b[3]);
        *(short8*)(wpb + i) = s;
    }
}

// ---------------- staging helpers (swizzled 64-col tiles) ----------------
template<int NROWS>
__device__ __forceinline__ void stage_rows(const u16* __restrict__ gbase, int ld,
                                           u16* lds_tile, int wid, int lane, int k0) {
#pragma unroll
    for (int i = 0; i < NROWS / 32; ++i) {
        int chunk = wid * (NROWS / 32) + i;
        int row = chunk * 8 + (lane >> 3);
        int pslot = lane & 7;
        const u16* gp = gbase + (size_t)row * ld + k0 + ((pslot ^ (row & 7)) << 3);
        u16* lp = lds_tile + chunk * 512;
        __builtin_amdgcn_global_load_lds((const __attribute__((address_space(1))) void*)gp,
                                         (__attribute__((address_space(3))) void*)lp, 16, 0, 0);
    }
}

__device__ __forceinline__ void stage_tile(const u16* __restrict__ gbase, int ld,
                                           u16* lds_tile, int wid, int lane, int k0) {
    stage_rows<128>(gbase, ld, lds_tile, wid, lane, k0);
}

__device__ __forceinline__ short8 read_frag(const u16* lds_tile, int row, int ks, int g) {
    int pslot = (ks * 4 + g) ^ (row & 7);
    return *(const short8*)&lds_tile[row * 64 + pslot * 8];
}

// Counted-vmcnt 2-deep pipeline body shared by both GEMMs.
#define GEMM_PIPE_LOOP(NT)                                                        \
    int cur = 0;                                                                  \
    for (int t = 0; t < (NT); ++t) {                                              \
        if (t < (NT) - 1) {                                                       \
            stage_tile(Ag, 384, &lds[cur ^ 1][0], wid, lane, (t + 1) * 64);       \
            stage_tile(Bg, 384, &lds[cur ^ 1][8192], wid, lane, (t + 1) * 64);    \
            asm volatile("s_waitcnt vmcnt(8)" ::: "memory");                      \
        } else {                                                                  \
            asm volatile("s_waitcnt vmcnt(0)" ::: "memory");                      \
        }                                                                         \
        __builtin_amdgcn_s_barrier();                                             \
        __builtin_amdgcn_sched_barrier(0);                                        \
        const u16* A = &lds[cur][0];                                              \
        const u16* Bm = &lds[cur][8192];                                          \
        short8 af[2][4], bf[2][4];                                                \
        _Pragma("unroll")                                                         \
        for (int ks = 0; ks < 2; ++ks) {                                          \
            _Pragma("unroll")                                                     \
            for (int mf = 0; mf < 4; ++mf) af[ks][mf] = read_frag(A, wm * 64 + mf * 16 + c, ks, g); \
            _Pragma("unroll")                                                     \
            for (int nf = 0; nf < 4; ++nf) bf[ks][nf] = read_frag(Bm, wn * 64 + nf * 16 + c, ks, g); \
        }                                                                         \
        _Pragma("unroll")                                                         \
        for (int ks = 0; ks < 2; ++ks)                                            \
            _Pragma("unroll")                                                     \
            for (int mf = 0; mf < 4; ++mf)                                        \
                _Pragma("unroll")                                                 \
                for (int nf = 0; nf < 4; ++nf)                                    \
                    acc[mf][nf] = __builtin_amdgcn_mfma_f32_16x16x32_bf16(af[ks][mf], bf[ks][nf], acc[mf][nf], 0, 0, 0); \
        __builtin_amdgcn_sched_barrier(0);                                        \
        __builtin_amdgcn_s_barrier();                                             \
        cur ^= 1;                                                                 \
    }

// ---------------- QKV GEMM: M=16384, N=1152, K=384 ----------------
// Persistent: 384 blocks x 3 jobs (wg, wg+384, wg+768). All blocks co-resident
// (384 <= 512 slots) -> zero dispatch tail. 384%8==0 keeps job xcd == block xcd,
// preserving the R11 XCD-chunked L2 locality (9 n-blocks of an m-tile on one XCD).
__global__ __launch_bounds__(256, 2) void k_gemm_qkv(const u16* __restrict__ xb, const u16* __restrict__ wb,
                                                     u16* __restrict__ q, u16* __restrict__ k,
                                                     u16* __restrict__ v) {
    __shared__ alignas(16) u16 lds[2][16384];
    const int tid = threadIdx.x, lane = tid & 63, wid = tid >> 6;
    const int wm = wid >> 1, wn = wid & 1, g = lane >> 4, c = lane & 15;
#pragma unroll 1
    for (int job = 0; job < 3; ++job) {
        const int wg = blockIdx.x + job * 384;
        const int xcd = wg & 7, q8 = wg >> 3;       // q8 in [0,144)
        const int mj = (q8 / 9) * 8 + xcd;          // m-group 0..127 (bijective)
        const int nk = q8 % 9;                      // n-block 0..8
        const int n0 = nk * 128, m0 = mj * 128;
        const u16* Ag = xb + (size_t)m0 * 384;
        const u16* Bg = wb + (size_t)n0 * 384;
        f32x4 acc[4][4] = {};
        stage_tile(Ag, 384, &lds[0][0], wid, lane, 0);
        stage_tile(Bg, 384, &lds[0][8192], wid, lane, 0);
        GEMM_PIPE_LOOP(6)
        const int which = n0 / 384;
        u16* dst = (which == 0) ? q : ((which == 1) ? k : v);
        const int h = ((n0 + wn * 64) % 384) / 64;
#pragma unroll
        for (int mf = 0; mf < 4; ++mf)
#pragma unroll
            for (int nf = 0; nf < 4; ++nf)
#pragma unroll
                for (int r = 0; r < 4; ++r) {
                    int m = m0 + wm * 64 + mf * 16 + g * 4 + r;
                    int d = nf * 16 + c;
                    int b = m >> 8, t = m & 255;
                    dst[((b * H_ + h) * T_ + t) * HD_ + d] = f2bf(acc[mf][nf][r]);
                }
    }
}

// ---------------- fused causal attention: q-fragment interleaved (R13, unchanged) ----------------
__global__ __launch_bounds__(256, 2) void k_attn(const u16* __restrict__ q, const u16* __restrict__ k,
                                                 const u16* __restrict__ v, u16* __restrict__ ao) {
    __shared__ alignas(16) u16 Kl[2][64 * 64];
    __shared__ alignas(16) u16 Vt[2][64][72];
    const int tid = threadIdx.x, bh = blockIdx.x;
    const int lane = tid & 63, wid = tid >> 6;
    const int g = lane >> 4, c = lane & 15;
    const int bq = bh * 256;

    const int vd0 = (tid & 15) * 4;
    const int vs0 = (tid >> 4) * 4;
    const int kb0 = ((vs0 >> 5) << 5) | (((vs0 >> 2) & 3) << 3) | (((vs0 >> 4) & 1) << 2);

    short8 qB[4][2];
#pragma unroll
    for (int qf = 0; qf < 4; ++qf)
#pragma unroll
        for (int ks = 0; ks < 2; ++ks) {
            int t = (qf * 4 + wid) * 16 + c;
            qB[qf][ks] = *(const short8*)&q[(bq + t) * 64 + ks * 32 + g * 8];
        }
    float mrun[4], lrun[4];
#pragma unroll
    for (int i = 0; i < 4; ++i) { mrun[i] = -1e30f; lrun[i] = 0.f; }
    f32x4 o[4][4] = {};

    short4_ vv[4];
    stage_rows<64>(k + (size_t)(bq) * 64, 64, &Kl[0][0], wid, lane, 0);
#pragma unroll
    for (int i = 0; i < 4; ++i)
        vv[i] = *(const short4_*)&v[(size_t)(bq + vs0 + i) * 64 + vd0];
#pragma unroll
    for (int j = 0; j < 4; ++j) {
        short4_ w4;
#pragma unroll
        for (int i = 0; i < 4; ++i) w4[i] = vv[i][j];
        *(short4_*)&Vt[0][vd0 + j][kb0] = w4;
    }
    __syncthreads();

#pragma unroll
    for (int kt = 0; kt < 4; ++kt) {
        const int buf = kt & 1;
        if (kt < 3) {
            stage_rows<64>(k + (size_t)(bq + (kt + 1) * 64) * 64, 64, &Kl[buf ^ 1][0], wid, lane, 0);
#pragma unroll
            for (int i = 0; i < 4; ++i)
                vv[i] = *(const short4_*)&v[(size_t)(bq + (kt + 1) * 64 + vs0 + i) * 64 + vd0];
        }
        {
            f32x4 st[4][4] = {};
            __builtin_amdgcn_s_setprio(1);
#pragma unroll
            for (int ks = 0; ks < 2; ++ks) {
                short8 kA[4];
#pragma unroll
                for (int sf = 0; sf < 4; ++sf)
                    kA[sf] = read_frag(&Kl[buf][0], sf * 16 + c, ks, g);
#pragma unroll
                for (int sf = 0; sf < 4; ++sf)
#pragma unroll
                    for (int qf = kt; qf < 4; ++qf)
                        st[sf][qf] = __builtin_amdgcn_mfma_f32_16x16x32_bf16(kA[sf], qB[qf][ks], st[sf][qf], 0, 0, 0);
            }
            __builtin_amdgcn_s_setprio(0);
            float pm[4];
#pragma unroll
            for (int qf = kt; qf < 4; ++qf) pm[qf] = -1e30f;
#pragma unroll
            for (int sf = 0; sf < 4; ++sf)
#pragma unroll
                for (int qf = kt; qf < 4; ++qf)
#pragma unroll
                    for (int r = 0; r < 4; ++r) {
                        float val = st[sf][qf][r] * 0.125f;
                        if (qf == kt) {
                            if (sf * 16 + g * 4 + r > 16 * wid + c) val = -1e30f;
                        }
                        st[sf][qf][r] = val;
                        pm[qf] = fmaxf(pm[qf], val);
                    }
            float alpha[4];
#pragma unroll
            for (int qf = kt; qf < 4; ++qf) {
                pm[qf] = fmaxf(pm[qf], __shfl_xor(pm[qf], 16));
                pm[qf] = fmaxf(pm[qf], __shfl_xor(pm[qf], 32));
                float mnew = fmaxf(mrun[qf], pm[qf]);
                alpha[qf] = __expf(mrun[qf] - mnew);
                mrun[qf] = mnew;
            }
            short8 pA[4][2];
#pragma unroll
            for (int qf = kt; qf < 4; ++qf) {
                float ls = 0.f;
#pragma unroll
                for (int ks = 0; ks < 2; ++ks) {
                    short8 pa;
#pragma unroll
                    for (int half = 0; half < 2; ++half) {
                        f32x4 sv = st[2 * ks + half][qf];
#pragma unroll
                        for (int r = 0; r < 4; ++r) {
                            float p = __expf(sv[r] - mrun[qf]);
                            ls += p;
                            pa[half * 4 + r] = (short)f2bf(p);
                        }
                    }
                    pA[qf][ks] = pa;
                }
                ls += __shfl_xor(ls, 16);
                ls += __shfl_xor(ls, 32);
                lrun[qf] = lrun[qf] * alpha[qf] + ls;
            }
#pragma unroll
            for (int qf = kt; qf < 4; ++qf)
#pragma unroll
                for (int r = 0; r < 4; ++r) {
                    float aof = __shfl(alpha[qf], g * 4 + r);
#pragma unroll
                    for (int df = 0; df < 4; ++df)
                        o[qf][df][r] *= aof;
                }
            __builtin_amdgcn_s_setprio(1);
#pragma unroll
            for (int ks = 0; ks < 2; ++ks) {
                short8 vB[4];
#pragma unroll
                for (int df = 0; df < 4; ++df)
                    vB[df] = *(short8*)&Vt[buf][df * 16 + c][ks * 32 + g * 8];
#pragma unroll
                for (int qf = kt; qf < 4; ++qf)
#pragma unroll
                    for (int df = 0; df < 4; ++df)
                        o[qf][df] = __builtin_amdgcn_mfma_f32_16x16x32_bf16(pA[qf][ks], vB[df], o[qf][df], 0, 0, 0);
            }
            __builtin_amdgcn_s_setprio(0);
        }
        if (kt < 3) {
#pragma unroll
            for (int j = 0; j < 4; ++j) {
                short4_ w4;
#pragma unroll
                for (int i = 0; i < 4; ++i) w4[i] = vv[i][j];
                *(short4_*)&Vt[buf ^ 1][vd0 + j][kb0] = w4;
            }
        }
        __syncthreads();
    }
    const int bb = bh / H_, hh = bh % H_;
#pragma unroll
    for (int qf = 0; qf < 4; ++qf)
#pragma unroll
        for (int r = 0; r < 4; ++r) {
            float inv = 1.0f / __shfl(lrun[qf], g * 4 + r);
            int t = (qf * 4 + wid) * 16 + g * 4 + r;
#pragma unroll
            for (int df = 0; df < 4; ++df) {
                int d = df * 16 + c;
                ao[((size_t)(bb * T_ + t)) * C_ + hh * 64 + d] = f2bf(o[qf][df][r] * inv);
            }
        }
}

// ---------------- output projection: M=16384, N=384, K=384 (R11, unchanged) ----------------
__global__ __launch_bounds__(256, 2) void k_gemm_proj(const u16* __restrict__ ab, const u16* __restrict__ wp,
                                                      const float* __restrict__ bp, float* __restrict__ out) {
    __shared__ alignas(16) u16 lds[2][16384];
    const int tid = threadIdx.x, lane = tid & 63, wid = tid >> 6;
    const int wm = wid >> 1, wn = wid & 1, g = lane >> 4, c = lane & 15;
    const int wg = blockIdx.x;
    const int xcd = wg & 7, q8 = wg >> 3;           // q8 in [0,48)
    const int mj = (q8 / 3) * 8 + xcd;              // m-group 0..127
    const int nk = q8 % 3;                          // n-block 0..2
    const int n0 = nk * 128, m0 = mj * 128;
    const u16* Ag = ab + (size_t)m0 * 384;
    const u16* Bg = wp + (size_t)n0 * 384;
    f32x4 acc[4][4] = {};
    stage_tile(Ag, 384, &lds[0][0], wid, lane, 0);
    stage_tile(Bg, 384, &lds[0][8192], wid, lane, 0);
    GEMM_PIPE_LOOP(6)
#pragma unroll
    for (int mf = 0; mf < 4; ++mf)
#pragma unroll
        for (int nf = 0; nf < 4; ++nf)
#pragma unroll
            for (int r = 0; r < 4; ++r) {
                int m = m0 + wm * 64 + mf * 16 + g * 4 + r;
                int n = n0 + wn * 64 + nf * 16 + c;
                out[(size_t)m * C_ + n] = acc[mf][nf][r] + bp[n];
            }
}

// ---------------- host ----------------

extern "C" void kernel_launch(void* const* d_in, const int* in_sizes, int n_in,
                              void* d_out, int out_size, void* d_ws, size_t ws_size,
                              hipStream_t stream) {
    const float* x  = (const float*)d_in[0];
    const float* Wq = (const float*)d_in[1];
    const float* Wk = (const float*)d_in[2];
    const float* Wv = (const float*)d_in[3];
    const float* Wp = (const float*)d_in[4];
    const float* bp = (const float*)d_in[5];
    float* out = (float*)d_out;

    char* ws = (char*)d_ws;
    u16* xb   = (u16*)(ws);                    // 16384*384 bf16
    u16* wqkv = (u16*)(ws + 12582912);         // 1152*384
    u16* wpb  = (u16*)(ws + 13467648);         // 384*384
    u16* qb   = (u16*)(ws + 13762560);         // 64*6*256*64
    u16* kb   = (u16*)(ws + 26345472);
    u16* vb   = (u16*)(ws + 38928384);
    u16* ab   = (u16*)(ws + 51511296);         // 16384*384 bf16

    k_prep<<<3252, 256, 0, stream>>>(x, Wq, Wk, Wv, Wp, xb, wqkv, wpb);
    k_gemm_qkv<<<384, 256, 0, stream>>>(xb, wqkv, qb, kb, vb);
    k_attn<<<384, 256, 0, stream>>>(qb, kb, vb, ab);
    k_gemm_proj<<<384, 256, 0, stream>>>(ab, wpb, bp, out);
}

// Round 20
// 61.672 us; speedup vs baseline: 1.0216x; 1.0216x over previous
//
#include <hip/hip_runtime.h>
#include <hip/hip_bf16.h>
#include <cstdint>
#include <cstddef>

#define B_ 64
#define T_ 256
#define C_ 384
#define H_ 6
#define HD_ 64

using u16 = unsigned short;
typedef __attribute__((ext_vector_type(8))) short short8;   // 8 bf16 (4 VGPR)
typedef __attribute__((ext_vector_type(4))) short short4_;  // 4 bf16 (8 B)
typedef __attribute__((ext_vector_type(4))) float f32x4;

__device__ __forceinline__ u16 f2bf(float f) {
    union { float f; uint32_t u; } x{f};
    uint32_t r = x.u + 0x7fffu + ((x.u >> 16) & 1u);
    return (u16)(r >> 16);
}

// ---------------- fused prep: cvt x, pack Wqkv (LDS transpose), cvt Wp ----------------
__global__ void k_prep(const float* __restrict__ x, const float* __restrict__ Wq,
                       const float* __restrict__ Wk, const float* __restrict__ Wv,
                       const float* __restrict__ Wp, u16* __restrict__ xb,
                       u16* __restrict__ wqkv, u16* __restrict__ wpb) {
    int bid = blockIdx.x;
    if (bid < 3072) {
        int i = (bid * 256 + threadIdx.x) * 8;
        const f32x4* p = (const f32x4*)(x + i);
        f32x4 a = p[0], b = p[1];
        short8 s;
        s[0] = (short)f2bf(a[0]); s[1] = (short)f2bf(a[1]);
        s[2] = (short)f2bf(a[2]); s[3] = (short)f2bf(a[3]);
        s[4] = (short)f2bf(b[0]); s[5] = (short)f2bf(b[1]);
        s[6] = (short)f2bf(b[2]); s[7] = (short)f2bf(b[3]);
        *(short8*)(xb + i) = s;
    } else if (bid < 3180) {
        __shared__ u16 Tt[64 * 65];
        int pb = bid - 3072;
        int which = pb / 36, rem = pb % 36;
        int h = rem / 6, cc0 = (rem % 6) * 64;
        const float* W = (which == 0) ? Wq : ((which == 1) ? Wk : Wv);
        int d = threadIdx.x & 63, cr0 = threadIdx.x >> 6;
#pragma unroll
        for (int p = 0; p < 16; ++p) {
            int cr = p * 4 + cr0;
            Tt[cr * 65 + d] = f2bf(W[(h * 384 + cc0 + cr) * 64 + d]);
        }
        __syncthreads();
        int ccl = threadIdx.x & 63, dl0 = threadIdx.x >> 6;
        int nbase = which * 384 + h * 64;
#pragma unroll
        for (int p = 0; p < 16; ++p) {
            int dl = p * 4 + dl0;
            wqkv[(size_t)(nbase + dl) * 384 + cc0 + ccl] = Tt[ccl * 65 + dl];
        }
    } else {
        int i = ((bid - 3180) * 256 + threadIdx.x) * 8;
        const f32x4* p = (const f32x4*)(Wp + i);
        f32x4 a = p[0], b = p[1];
        short8 s;
        s[0] = (short)f2bf(a[0]); s[1] = (short)f2bf(a[1]);
        s[2] = (short)f2bf(a[2]); s[3] = (short)f2bf(a[3]);
        s[4] = (short)f2bf(b[0]); s[5] = (short)f2bf(b[1]);
        s[6] = (short)f2bf(b[2]); s[7] = (short)f2bf(b[3]);
        *(short8*)(wpb + i) = s;
    }
}

// ---------------- staging helpers (swizzled 64-col tiles) ----------------
template<int NROWS>
__device__ __forceinline__ void stage_rows(const u16* __restrict__ gbase, int ld,
                                           u16* lds_tile, int wid, int lane, int k0) {
#pragma unroll
    for (int i = 0; i < NROWS / 32; ++i) {
        int chunk = wid * (NROWS / 32) + i;
        int row = chunk * 8 + (lane >> 3);
        int pslot = lane & 7;
        const u16* gp = gbase + (size_t)row * ld + k0 + ((pslot ^ (row & 7)) << 3);
        u16* lp = lds_tile + chunk * 512;
        __builtin_amdgcn_global_load_lds((const __attribute__((address_space(1))) void*)gp,
                                         (__attribute__((address_space(3))) void*)lp, 16, 0, 0);
    }
}

__device__ __forceinline__ void stage_tile(const u16* __restrict__ gbase, int ld,
                                           u16* lds_tile, int wid, int lane, int k0) {
    stage_rows<128>(gbase, ld, lds_tile, wid, lane, k0);
}

__device__ __forceinline__ short8 read_frag(const u16* lds_tile, int row, int ks, int g) {
    int pslot = (ks * 4 + g) ^ (row & 7);
    return *(const short8*)&lds_tile[row * 64 + pslot * 8];
}

// Counted-vmcnt 2-deep pipeline body shared by both GEMMs.
#define GEMM_PIPE_LOOP(NT)                                                        \
    int cur = 0;                                                                  \
    for (int t = 0; t < (NT); ++t) {                                              \
        if (t < (NT) - 1) {                                                       \
            stage_tile(Ag, 384, &lds[cur ^ 1][0], wid, lane, (t + 1) * 64);       \
            stage_tile(Bg, 384, &lds[cur ^ 1][8192], wid, lane, (t + 1) * 64);    \
            asm volatile("s_waitcnt vmcnt(8)" ::: "memory");                      \
        } else {                                                                  \
            asm volatile("s_waitcnt vmcnt(0)" ::: "memory");                      \
        }                                                                         \
        __builtin_amdgcn_s_barrier();                                             \
        __builtin_amdgcn_sched_barrier(0);                                        \
        const u16* A = &lds[cur][0];                                              \
        const u16* Bm = &lds[cur][8192];                                          \
        short8 af[2][4], bf[2][4];                                                \
        _Pragma("unroll")                                                         \
        for (int ks = 0; ks < 2; ++ks) {                                          \
            _Pragma("unroll")                                                     \
            for (int mf = 0; mf < 4; ++mf) af[ks][mf] = read_frag(A, wm * 64 + mf * 16 + c, ks, g); \
            _Pragma("unroll")                                                     \
            for (int nf = 0; nf < 4; ++nf) bf[ks][nf] = read_frag(Bm, wn * 64 + nf * 16 + c, ks, g); \
        }                                                                         \
        _Pragma("unroll")                                                         \
        for (int ks = 0; ks < 2; ++ks)                                            \
            _Pragma("unroll")                                                     \
            for (int mf = 0; mf < 4; ++mf)                                        \
                _Pragma("unroll")                                                 \
                for (int nf = 0; nf < 4; ++nf)                                    \
                    acc[mf][nf] = __builtin_amdgcn_mfma_f32_16x16x32_bf16(af[ks][mf], bf[ks][nf], acc[mf][nf], 0, 0, 0); \
        __builtin_amdgcn_sched_barrier(0);                                        \
        __builtin_amdgcn_s_barrier();                                             \
        cur ^= 1;                                                                 \
    }

// ---------------- QKV GEMM: M=16384, N=1152, K=384 ----------------
// 1D grid 1152, XCD-chunked swizzle: the 9 n-blocks sharing one m-tile are
// consecutive on ONE XCD so the x-tile is fetched into that XCD's L2 once.
__global__ __launch_bounds__(256, 2) void k_gemm_qkv(const u16* __restrict__ xb, const u16* __restrict__ wb,
                                                     u16* __restrict__ q, u16* __restrict__ k,
                                                     u16* __restrict__ v) {
    __shared__ alignas(16) u16 lds[2][16384];
    const int tid = threadIdx.x, lane = tid & 63, wid = tid >> 6;
    const int wm = wid >> 1, wn = wid & 1, g = lane >> 4, c = lane & 15;
    const int wg = blockIdx.x;
    const int xcd = wg & 7, q8 = wg >> 3;           // q8 in [0,144)
    const int mj = (q8 / 9) * 8 + xcd;              // m-group 0..127 (bijective)
    const int nk = q8 % 9;                          // n-block 0..8
    const int n0 = nk * 128, m0 = mj * 128;
    const u16* Ag = xb + (size_t)m0 * 384;
    const u16* Bg = wb + (size_t)n0 * 384;
    f32x4 acc[4][4] = {};
    stage_tile(Ag, 384, &lds[0][0], wid, lane, 0);
    stage_tile(Bg, 384, &lds[0][8192], wid, lane, 0);
    GEMM_PIPE_LOOP(6)
    const int which = n0 / 384;
    u16* dst = (which == 0) ? q : ((which == 1) ? k : v);
    const int h = ((n0 + wn * 64) % 384) / 64;
#pragma unroll
    for (int mf = 0; mf < 4; ++mf)
#pragma unroll
        for (int nf = 0; nf < 4; ++nf)
#pragma unroll
            for (int r = 0; r < 4; ++r) {
                int m = m0 + wm * 64 + mf * 16 + g * 4 + r;
                int d = nf * 16 + c;
                int b = m >> 8, t = m & 255;
                dst[((b * H_ + h) * T_ + t) * HD_ + d] = f2bf(acc[mf][nf][r]);
            }
}

// ---------------- fused causal attention: q-fragment interleaved (balanced waves) ----------------
// Wave w owns q-frags {w, 4+w, 8+w, 12+w} (frag_id = qf*4+wid, 16 rows each).
// At tile kt every wave has exactly (4-kt) active frags -> no causal wave idle.
// Frag qf crosses the diagonal iff qf == kt; mask: sf*16+4g+r > 16*wid+c.
__global__ __launch_bounds__(256, 2) void k_attn(const u16* __restrict__ q, const u16* __restrict__ k,
                                                 const u16* __restrict__ v, u16* __restrict__ ao) {
    __shared__ alignas(16) u16 Kl[2][64 * 64];
    __shared__ alignas(16) u16 Vt[2][64][72];
    const int tid = threadIdx.x, bh = blockIdx.x;
    const int lane = tid & 63, wid = tid >> 6;
    const int g = lane >> 4, c = lane & 15;
    const int bq = bh * 256;

    const int vd0 = (tid & 15) * 4;
    const int vs0 = (tid >> 4) * 4;
    const int kb0 = ((vs0 >> 5) << 5) | (((vs0 >> 2) & 3) << 3) | (((vs0 >> 4) & 1) << 2);

    short8 qB[4][2];
#pragma unroll
    for (int qf = 0; qf < 4; ++qf)
#pragma unroll
        for (int ks = 0; ks < 2; ++ks) {
            int t = (qf * 4 + wid) * 16 + c;
            qB[qf][ks] = *(const short8*)&q[(bq + t) * 64 + ks * 32 + g * 8];
        }
    float mrun[4], lrun[4];
#pragma unroll
    for (int i = 0; i < 4; ++i) { mrun[i] = -1e30f; lrun[i] = 0.f; }
    f32x4 o[4][4] = {};

    short4_ vv[4];
    stage_rows<64>(k + (size_t)(bq) * 64, 64, &Kl[0][0], wid, lane, 0);
#pragma unroll
    for (int i = 0; i < 4; ++i)
        vv[i] = *(const short4_*)&v[(size_t)(bq + vs0 + i) * 64 + vd0];
#pragma unroll
    for (int j = 0; j < 4; ++j) {
        short4_ w4;
#pragma unroll
        for (int i = 0; i < 4; ++i) w4[i] = vv[i][j];
        *(short4_*)&Vt[0][vd0 + j][kb0] = w4;
    }
    __syncthreads();

#pragma unroll
    for (int kt = 0; kt < 4; ++kt) {
        const int buf = kt & 1;
        if (kt < 3) {
            stage_rows<64>(k + (size_t)(bq + (kt + 1) * 64) * 64, 64, &Kl[buf ^ 1][0], wid, lane, 0);
#pragma unroll
            for (int i = 0; i < 4; ++i)
                vv[i] = *(const short4_*)&v[(size_t)(bq + (kt + 1) * 64 + vs0 + i) * 64 + vd0];
        }
        {
            f32x4 st[4][4] = {};
            __builtin_amdgcn_s_setprio(1);
#pragma unroll
            for (int ks = 0; ks < 2; ++ks) {
                short8 kA[4];
#pragma unroll
                for (int sf = 0; sf < 4; ++sf)
                    kA[sf] = read_frag(&Kl[buf][0], sf * 16 + c, ks, g);
#pragma unroll
                for (int sf = 0; sf < 4; ++sf)
#pragma unroll
                    for (int qf = kt; qf < 4; ++qf)
                        st[sf][qf] = __builtin_amdgcn_mfma_f32_16x16x32_bf16(kA[sf], qB[qf][ks], st[sf][qf], 0, 0, 0);
            }
            __builtin_amdgcn_s_setprio(0);
            float pm[4];
#pragma unroll
            for (int qf = kt; qf < 4; ++qf) pm[qf] = -1e30f;
#pragma unroll
            for (int sf = 0; sf < 4; ++sf)
#pragma unroll
                for (int qf = kt; qf < 4; ++qf)
#pragma unroll
                    for (int r = 0; r < 4; ++r) {
                        float val = st[sf][qf][r] * 0.125f;
                        if (qf == kt) {
                            if (sf * 16 + g * 4 + r > 16 * wid + c) val = -1e30f;
                        }
                        st[sf][qf][r] = val;
                        pm[qf] = fmaxf(pm[qf], val);
                    }
            float alpha[4];
#pragma unroll
            for (int qf = kt; qf < 4; ++qf) {
                pm[qf] = fmaxf(pm[qf], __shfl_xor(pm[qf], 16));
                pm[qf] = fmaxf(pm[qf], __shfl_xor(pm[qf], 32));
                float mnew = fmaxf(mrun[qf], pm[qf]);
                alpha[qf] = __expf(mrun[qf] - mnew);
                mrun[qf] = mnew;
            }
            short8 pA[4][2];
#pragma unroll
            for (int qf = kt; qf < 4; ++qf) {
                float ls = 0.f;
#pragma unroll
                for (int ks = 0; ks < 2; ++ks) {
                    short8 pa;
#pragma unroll
                    for (int half = 0; half < 2; ++half) {
                        f32x4 sv = st[2 * ks + half][qf];
#pragma unroll
                        for (int r = 0; r < 4; ++r) {
                            float p = __expf(sv[r] - mrun[qf]);
                            ls += p;
                            pa[half * 4 + r] = (short)f2bf(p);
                        }
                    }
                    pA[qf][ks] = pa;
                }
                ls += __shfl_xor(ls, 16);
                ls += __shfl_xor(ls, 32);
                lrun[qf] = lrun[qf] * alpha[qf] + ls;
            }
#pragma unroll
            for (int qf = kt; qf < 4; ++qf)
#pragma unroll
                for (int r = 0; r < 4; ++r) {
                    float aof = __shfl(alpha[qf], g * 4 + r);
#pragma unroll
                    for (int df = 0; df < 4; ++df)
                        o[qf][df][r] *= aof;
                }
            __builtin_amdgcn_s_setprio(1);
#pragma unroll
            for (int ks = 0; ks < 2; ++ks) {
                short8 vB[4];
#pragma unroll
                for (int df = 0; df < 4; ++df)
                    vB[df] = *(short8*)&Vt[buf][df * 16 + c][ks * 32 + g * 8];
#pragma unroll
                for (int qf = kt; qf < 4; ++qf)
#pragma unroll
                    for (int df = 0; df < 4; ++df)
                        o[qf][df] = __builtin_amdgcn_mfma_f32_16x16x32_bf16(pA[qf][ks], vB[df], o[qf][df], 0, 0, 0);
            }
            __builtin_amdgcn_s_setprio(0);
        }
        if (kt < 3) {
#pragma unroll
            for (int j = 0; j < 4; ++j) {
                short4_ w4;
#pragma unroll
                for (int i = 0; i < 4; ++i) w4[i] = vv[i][j];
                *(short4_*)&Vt[buf ^ 1][vd0 + j][kb0] = w4;
            }
        }
        __syncthreads();
    }
    const int bb = bh / H_, hh = bh % H_;
#pragma unroll
    for (int qf = 0; qf < 4; ++qf)
#pragma unroll
        for (int r = 0; r < 4; ++r) {
            float inv = 1.0f / __shfl(lrun[qf], g * 4 + r);
            int t = (qf * 4 + wid) * 16 + g * 4 + r;
#pragma unroll
            for (int df = 0; df < 4; ++df) {
                int d = df * 16 + c;
                ao[((size_t)(bb * T_ + t)) * C_ + hh * 64 + d] = f2bf(o[qf][df][r] * inv);
            }
        }
}

// ---------------- output projection: M=16384, N=384, K=384 (R11, unchanged) ----------------
__global__ __launch_bounds__(256, 2) void k_gemm_proj(const u16* __restrict__ ab, const u16* __restrict__ wp,
                                                      const float* __restrict__ bp, float* __restrict__ out) {
    __shared__ alignas(16) u16 lds[2][16384];
    const int tid = threadIdx.x, lane = tid & 63, wid = tid >> 6;
    const int wm = wid >> 1, wn = wid & 1, g = lane >> 4, c = lane & 15;
    const int wg = blockIdx.x;
    const int xcd = wg & 7, q8 = wg >> 3;           // q8 in [0,48)
    const int mj = (q8 / 3) * 8 + xcd;              // m-group 0..127
    const int nk = q8 % 3;                          // n-block 0..2
    const int n0 = nk * 128, m0 = mj * 128;
    const u16* Ag = ab + (size_t)m0 * 384;
    const u16* Bg = wp + (size_t)n0 * 384;
    f32x4 acc[4][4] = {};
    stage_tile(Ag, 384, &lds[0][0], wid, lane, 0);
    stage_tile(Bg, 384, &lds[0][8192], wid, lane, 0);
    GEMM_PIPE_LOOP(6)
#pragma unroll
    for (int mf = 0; mf < 4; ++mf)
#pragma unroll
        for (int nf = 0; nf < 4; ++nf)
#pragma unroll
            for (int r = 0; r < 4; ++r) {
                int m = m0 + wm * 64 + mf * 16 + g * 4 + r;
                int n = n0 + wn * 64 + nf * 16 + c;
                out[(size_t)m * C_ + n] = acc[mf][nf][r] + bp[n];
            }
}

// ---------------- host ----------------

extern "C" void kernel_launch(void* const* d_in, const int* in_sizes, int n_in,
                              void* d_out, int out_size, void* d_ws, size_t ws_size,
                              hipStream_t stream) {
    const float* x  = (const float*)d_in[0];
    const float* Wq = (const float*)d_in[1];
    const float* Wk = (const float*)d_in[2];
    const float* Wv = (const float*)d_in[3];
    const float* Wp = (const float*)d_in[4];
    const float* bp = (const float*)d_in[5];
    float* out = (float*)d_out;

    char* ws = (char*)d_ws;
    u16* xb   = (u16*)(ws);                    // 16384*384 bf16
    u16* wqkv = (u16*)(ws + 12582912);         // 1152*384
    u16* wpb  = (u16*)(ws + 13467648);         // 384*384
    u16* qb   = (u16*)(ws + 13762560);         // 64*6*256*64
    u16* kb   = (u16*)(ws + 26345472);
    u16* vb   = (u16*)(ws + 38928384);
    u16* ab   = (u16*)(ws + 51511296);         // 16384*384 bf16

    k_prep<<<3252, 256, 0, stream>>>(x, Wq, Wk, Wv, Wp, xb, wqkv, wpb);
    k_gemm_qkv<<<1152, 256, 0, stream>>>(xb, wqkv, qb, kb, vb);
    k_attn<<<384, 256, 0, stream>>>(qb, kb, vb, ab);
    k_gemm_proj<<<384, 256, 0, stream>>>(ab, wpb, bp, out);
}